// Round 3
// baseline (231.272 us; speedup 1.0000x reference)
//
#include <hip/hip_runtime.h>
#include <hip/hip_fp16.h>
#include <math.h>

#define FACE_W 256
#define CH 32
#define BATCH 2
#define OUT_H (2 * FACE_W)            // 512
#define OUT_W (4 * FACE_W)            // 1024
#define N_PIX (OUT_H * OUT_W)         // 524288 = 2^19
#define PLANE (FACE_W * FACE_W)       // 65536
#define FACE_STRIDE (CH * PLANE)      // 2^21 floats
#define BATCH_STRIDE (6 * FACE_STRIDE)
#define OUT_PLANE (OUT_H * OUT_W)

// fp16 intermediate: (b, f, pixel, ch) halfs.  48 MiB.
#define TRANS_H_ELEMS ((size_t)BATCH * 6 * PLANE * CH)
#define TRANS_H_BYTES (TRANS_H_ELEMS * 2)            // 48 MiB
#define REC_BYTES     ((size_t)N_PIX * 8)            // 4 MiB (uint2 records)
#define BATCH_H_STRIDE ((size_t)6 * PLANE * CH)      // halfs per batch

// prep: 3072 transpose blocks (256 px x 32 ch) + 2048 grid blocks,
// interleaved 3:2 by blockIdx so VALU-heavy grid blocks are co-resident
// with BW-heavy transpose blocks for the whole dispatch (not a serial tail).
#define TPOSE_BLOCKS (BATCH * 6 * (PLANE / 256))     // 3072
#define GRID_BLOCKS  (N_PIX / 256)                   // 2048
#define PREP_BLOCKS  (TPOSE_BLOCKS + GRID_BLOCKS)    // 5120
#define SAMPLE_BLOCKS ((N_PIX * 4) / 256)            // 8192

typedef float f4 __attribute__((ext_vector_type(4)));

__device__ __forceinline__ float2 h2f2(unsigned u) {
    union { unsigned u; __half2 h; } c;
    c.u = u;
    return __half22float2(c.h);
}
__device__ __forceinline__ unsigned packh2(float a, float b) {
    union { __half2 h; unsigned u; } c;
    c.h = __halves2half2(__float2half(a), __float2half(b));
    return c.u;
}

// ---------------- Kernel A: transpose->fp16 + grid math, interleaved --------
__global__ __launch_bounds__(256) void prep_kernel(
    const float* __restrict__ in, ushort* __restrict__ out_h,
    uint2* __restrict__ rec) {
    unsigned grp = blockIdx.x / 5;
    unsigned r   = blockIdx.x % 5;            // 5120 = 1024 * (2 grid + 3 tpose)
    if (r >= 2) {
        // ---- transpose path: 256 pixels x 32 channels per block ----
        // Loads: float4 nontemporal (input single-use; keep LLC for in_h).
        // Stores: dwordx4, 64 B/pixel channel-last, fully contiguous.
        // LDS: stride 34 ushorts; read phase dword-granular at dword-stride
        // 17 -> bank = 17p mod 32 bijective, conflict-free.
        int tb = grp * 3 + (r - 2);           // [0, 3072)
        __shared__ ushort tile[256][CH + 2];  // stride 34 ushorts = 68 B
        int bf  = tb >> 8;                    // (b*6+face) in [0,12)
        int p0  = (tb & 255) << 8;            // 256-pixel tile base
        int tid = threadIdx.x;
        int l = tid & 63, w = tid >> 6;       // lane, wave

        const float* src = in + (size_t)bf * FACE_STRIDE + p0 + 4 * l;
        f4 A[4], B[4];
        #pragma unroll
        for (int it = 0; it < 4; ++it) {
            int cp = it * 4 + w;              // channel pair 0..15
            A[it] = __builtin_nontemporal_load(
                        (const f4*)(src + (size_t)(2 * cp) * PLANE));
            B[it] = __builtin_nontemporal_load(
                        (const f4*)(src + (size_t)(2 * cp + 1) * PLANE));
        }
        #pragma unroll
        for (int it = 0; it < 4; ++it) {
            int cp = it * 4 + w;
            #pragma unroll
            for (int i = 0; i < 4; ++i)
                *(unsigned*)&tile[4 * l + i][2 * cp] = packh2(A[it][i], B[it][i]);
        }
        __syncthreads();

        const ushort* row = tile[tid];
        uint4* dst = (uint4*)(out_h + ((size_t)bf * PLANE + p0 + tid) * CH);
        #pragma unroll
        for (int q = 0; q < 4; ++q) {
            unsigned u0 = *(const unsigned*)&row[8 * q + 0];
            unsigned u1 = *(const unsigned*)&row[8 * q + 2];
            unsigned u2 = *(const unsigned*)&row[8 * q + 4];
            unsigned u3 = *(const unsigned*)&row[8 * q + 6];
            dst[q] = make_uint4(u0, u1, u2, u3);
        }
    } else {
        // ---- grid path: fp64 keeps face decisions off cube-edge
        // boundaries (verified: absmax 0.03125 vs threshold 0.096) ----
        int pix = (grp * 2 + r) * 256 + threadIdx.x;
        int xx = pix & (OUT_W - 1);
        int yy = pix >> 10;

        const double PI = 3.14159265358979323846;
        double theta = (2.0 * (xx + 0.5) / OUT_W - 1.0) * PI;
        double phi   = (2.0 * (yy + 0.5) / OUT_H - 1.0) * (PI * 0.5);
        double st, ct, sp, cp;
        sincos(theta, &st, &ct);
        sincos(phi, &sp, &cp);
        double sx = cp * ct;
        double sy = cp * st;
        double sz = sp;
        double ax = fabs(sx), ay = fabs(sy), az = fabs(sz);

        const double EPS = 1e-9;
        int face;
        double u, v;
        if (ax >= ay && ax >= az) {
            face = (sx >= 0.0) ? 0 : 1;
            double d = fmax(ax, EPS);
            u = ((face == 0) ? sy : -sy) / d;
            v = sz / d;
        } else if (ay >= az) {
            face = (sy >= 0.0) ? 2 : 3;
            double d = fmax(ay, EPS);
            u = ((face == 2) ? -sx : sx) / d;
            v = sz / d;
        } else {
            face = (sz >= 0.0) ? 4 : 5;
            double d = fmax(az, EPS);
            u = sy / d;
            v = ((face == 4) ? -sx : sx) / d;
        }

        float px = (float)((u + 1.0) * 0.5 * (FACE_W - 1));
        float py = (float)((v + 1.0) * 0.5 * (FACE_W - 1));
        float fx0 = floorf(px), fy0 = floorf(py);
        float wx = px - fx0, wy = py - fy0;
        int x0 = min(max((int)fx0, 0), FACE_W - 1);
        int y0 = min(max((int)fy0, 0), FACE_W - 1);

        unsigned off00 = ((unsigned)face << 16) | (unsigned)(y0 * FACE_W + x0);
        unsigned wpack = (unsigned)__half_as_ushort(__float2half(wx)) |
                         ((unsigned)__half_as_ushort(__float2half(wy)) << 16);
        rec[pix] = make_uint2(off00, wpack);
    }
}

// ---------------- Kernel B: gather+blend on channel-last fp16 data ----------
// 4 lanes per pixel; each lane owns 8 consecutive channels -> every corner
// gather is a 16 B contiguous uint4.  ALL 8 gathers (4 corners x 2 batches)
// issue before any blend: max memory-level parallelism per thread.
// Output stores NONTEMPORAL (128 MiB write-once must not evict the 48 MiB
// in_h gather set from L2/LLC).  Bijective XCD-chunk swizzle keeps each
// XCD's gather footprint in its private L2.
__global__ __launch_bounds__(256) void sample_h_kernel(
    const ushort* __restrict__ in_h, const uint2* __restrict__ rec,
    float* __restrict__ out) {
    unsigned bid = (blockIdx.x & 7) * (SAMPLE_BLOCKS / 8) + (blockIdx.x >> 3);
    unsigned g = bid * blockDim.x + threadIdx.x;
    int cg  = g & 3;                 // channel group (8 ch each)
    int pix = g >> 2;

    uint2 r = rec[pix];
    int face  = r.x >> 16;
    int pix16 = r.x & 0xFFFF;
    int x0 = r.x & 255;
    int y0 = (r.x >> 8) & 255;
    float wx = __half2float(__ushort_as_half((ushort)(r.y & 0xFFFF)));
    float wy = __half2float(__ushort_as_half((ushort)(r.y >> 16)));
    int dxE = (x0 < FACE_W - 1) ? CH : 0;              // +1 in x -> +32 halfs
    int dyE = (y0 < FACE_W - 1) ? FACE_W * CH : 0;     // +1 in y -> +8192 halfs

    const ushort* s0 = in_h + ((size_t)face * PLANE + pix16) * CH + cg * 8;
    const ushort* s1 = s0 + BATCH_H_STRIDE;

    uint4 qa00 = *(const uint4*)(s0);
    uint4 qa10 = *(const uint4*)(s0 + dxE);
    uint4 qa01 = *(const uint4*)(s0 + dyE);
    uint4 qa11 = *(const uint4*)(s0 + dxE + dyE);
    uint4 qb00 = *(const uint4*)(s1);
    uint4 qb10 = *(const uint4*)(s1 + dxE);
    uint4 qb01 = *(const uint4*)(s1 + dyE);
    uint4 qb11 = *(const uint4*)(s1 + dxE + dyE);

    float w00 = (1.0f - wx) * (1.0f - wy);
    float w10 = wx * (1.0f - wy);
    float w01 = (1.0f - wx) * wy;
    float w11 = wx * wy;

    float* ob0 = out + ((size_t)(cg * 8)) * OUT_PLANE + pix;
    #pragma unroll
    for (int j = 0; j < 4; ++j) {
        float2 f00 = h2f2(((const unsigned*)&qa00)[j]);
        float2 f10 = h2f2(((const unsigned*)&qa10)[j]);
        float2 f01 = h2f2(((const unsigned*)&qa01)[j]);
        float2 f11 = h2f2(((const unsigned*)&qa11)[j]);
        __builtin_nontemporal_store(
            f00.x * w00 + f10.x * w10 + f01.x * w01 + f11.x * w11,
            &ob0[(size_t)(2 * j) * OUT_PLANE]);
        __builtin_nontemporal_store(
            f00.y * w00 + f10.y * w10 + f01.y * w01 + f11.y * w11,
            &ob0[(size_t)(2 * j + 1) * OUT_PLANE]);
    }
    float* ob1 = ob0 + (size_t)CH * OUT_PLANE;
    #pragma unroll
    for (int j = 0; j < 4; ++j) {
        float2 f00 = h2f2(((const unsigned*)&qb00)[j]);
        float2 f10 = h2f2(((const unsigned*)&qb10)[j]);
        float2 f01 = h2f2(((const unsigned*)&qb01)[j]);
        float2 f11 = h2f2(((const unsigned*)&qb11)[j]);
        __builtin_nontemporal_store(
            f00.x * w00 + f10.x * w10 + f01.x * w01 + f11.x * w11,
            &ob1[(size_t)(2 * j) * OUT_PLANE]);
        __builtin_nontemporal_store(
            f00.y * w00 + f10.y * w10 + f01.y * w01 + f11.y * w11,
            &ob1[(size_t)(2 * j + 1) * OUT_PLANE]);
    }
}

// ---------------- Fallback: fully fused (tiny workspace) --------------------
__global__ __launch_bounds__(256) void cube2equi_fused(
    const float* __restrict__ in, float* __restrict__ out) {
    int pix = blockIdx.x * blockDim.x + threadIdx.x;
    if (pix >= N_PIX) return;
    int xx = pix & (OUT_W - 1);
    int yy = pix >> 10;

    const double PI = 3.14159265358979323846;
    double theta = (2.0 * (xx + 0.5) / OUT_W - 1.0) * PI;
    double phi   = (2.0 * (yy + 0.5) / OUT_H - 1.0) * (PI * 0.5);
    double cph = cos(phi);
    double sx = cph * cos(theta);
    double sy = cph * sin(theta);
    double sz = sin(phi);
    double ax = fabs(sx), ay = fabs(sy), az = fabs(sz);

    const double EPS = 1e-9;
    int face;
    double u, v;
    if (ax >= ay && ax >= az) {
        face = (sx >= 0.0) ? 0 : 1;
        double d = fmax(ax, EPS);
        u = ((face == 0) ? sy : -sy) / d;
        v = sz / d;
    } else if (ay >= az) {
        face = (sy >= 0.0) ? 2 : 3;
        double d = fmax(ay, EPS);
        u = ((face == 2) ? -sx : sx) / d;
        v = sz / d;
    } else {
        face = (sz >= 0.0) ? 4 : 5;
        double d = fmax(az, EPS);
        u = sy / d;
        v = ((face == 4) ? -sx : sx) / d;
    }

    float px = (float)((u + 1.0) * 0.5 * (FACE_W - 1));
    float py = (float)((v + 1.0) * 0.5 * (FACE_W - 1));
    float fx0 = floorf(px), fy0 = floorf(py);
    float wx = px - fx0, wy = py - fy0;
    int x0 = min(max((int)fx0, 0), FACE_W - 1);
    int x1 = min(max((int)fx0 + 1, 0), FACE_W - 1);
    int y0 = min(max((int)fy0, 0), FACE_W - 1);
    int y1 = min(max((int)fy0 + 1, 0), FACE_W - 1);

    float w00 = (1.0f - wx) * (1.0f - wy);
    float w10 = wx * (1.0f - wy);
    float w01 = (1.0f - wx) * wy;
    float w11 = wx * wy;

    int o00 = y0 * FACE_W + x0;
    int o10 = y0 * FACE_W + x1;
    int o01 = y1 * FACE_W + x0;
    int o11 = y1 * FACE_W + x1;

    const float* fbase = in + (size_t)face * FACE_STRIDE;

    for (int b = 0; b < BATCH; ++b) {
        const float* bb = fbase + (size_t)b * BATCH_STRIDE;
        float* obp = out + (size_t)b * CH * OUT_PLANE + pix;
        #pragma unroll 4
        for (int c = 0; c < CH; ++c) {
            const float* p = bb + (size_t)c * PLANE;
            obp[(size_t)c * OUT_PLANE] = p[o00] * w00 + p[o10] * w10 +
                                         p[o01] * w01 + p[o11] * w11;
        }
    }
}

extern "C" void kernel_launch(void* const* d_in, const int* in_sizes, int n_in,
                              void* d_out, int out_size, void* d_ws, size_t ws_size,
                              hipStream_t stream) {
    const float* in = (const float*)d_in[0];
    float* out = (float*)d_out;

    if (ws_size >= TRANS_H_BYTES + REC_BYTES) {
        ushort* in_h = (ushort*)d_ws;
        uint2* rec = (uint2*)((char*)d_ws + TRANS_H_BYTES);
        prep_kernel<<<PREP_BLOCKS, 256, 0, stream>>>(in, in_h, rec);
        sample_h_kernel<<<SAMPLE_BLOCKS, 256, 0, stream>>>(in_h, rec, out);
    } else {
        cube2equi_fused<<<N_PIX / 256, 256, 0, stream>>>(in, out);
    }
}